// Round 1
// baseline (250.498 us; speedup 1.0000x reference)
//
#include <hip/hip_runtime.h>
#include <math.h>

// DeepseekV3 TopK router, MI355X.
// One thread per token. Branchless per-group sorted top-8 lists in VGPRs,
// bitonic top-8 merge tree for the final selection. No LDS, no shuffles.

constexpr int N_EXPERTS   = 256;
constexpr int N_GROUP     = 8;
constexpr int EG          = 32;   // experts per group
constexpr int TOPK_GROUP  = 4;
constexpr int TOP_K       = 8;

// Insert (v,i) into a descending sorted-8 list. Strict '>' keeps
// lower-index-first on ties (stream indices are ascending).
__device__ __forceinline__ void insert8(float (&lv)[8], float (&li)[8], float v, float i) {
#pragma unroll
  for (int k = 0; k < 8; ++k) {
    const bool gt = v > lv[k];
    const float nv = gt ? lv[k] : v;
    const float ni = gt ? li[k] : i;
    lv[k] = gt ? v : lv[k];
    li[k] = gt ? i : li[k];
    v = nv; i = ni;
  }
}

// Total order: (value desc, index asc on ties).
__device__ __forceinline__ bool keyGE(float va, float ia, float vb, float ib) {
  return (va > vb) || (va == vb && ia < ib);
}

__device__ __forceinline__ void takeMax(float va, float ia, float vb, float ib,
                                        float& vo, float& io) {
  const bool a = keyGE(va, ia, vb, ib);
  vo = a ? va : vb;
  io = a ? ia : ib;
}

__device__ __forceinline__ void cswap(float& va, float& ia, float& vb, float& ib) {
  const bool a = keyGE(va, ia, vb, ib);
  const float v1 = a ? va : vb, i1 = a ? ia : ib;
  const float v2 = a ? vb : va, i2 = a ? ib : ia;
  va = v1; ia = i1; vb = v2; ib = i2;
}

// Top-8 of two descending sorted-8 lists -> descending sorted-8.
// Partner-max (bitonic first stage) + bitonic sort of the bitonic survivor seq.
__device__ __forceinline__ void merge8(const float (&Av)[8], const float (&Ai)[8],
                                       const float (&Bv)[8], const float (&Bi)[8],
                                       float (&Rv)[8], float (&Ri)[8]) {
#pragma unroll
  for (int i = 0; i < 8; ++i) takeMax(Av[i], Ai[i], Bv[7 - i], Bi[7 - i], Rv[i], Ri[i]);
  // bitonic sort, distances 4, 2, 1 (descending)
#pragma unroll
  for (int i = 0; i < 4; ++i) cswap(Rv[i], Ri[i], Rv[i + 4], Ri[i + 4]);
  cswap(Rv[0], Ri[0], Rv[2], Ri[2]);
  cswap(Rv[1], Ri[1], Rv[3], Ri[3]);
  cswap(Rv[4], Ri[4], Rv[6], Ri[6]);
  cswap(Rv[5], Ri[5], Rv[7], Ri[7]);
  cswap(Rv[0], Ri[0], Rv[1], Ri[1]);
  cswap(Rv[2], Ri[2], Rv[3], Ri[3]);
  cswap(Rv[4], Ri[4], Rv[5], Ri[5]);
  cswap(Rv[6], Ri[6], Rv[7], Ri[7]);
}

__global__ __launch_bounds__(256, 2) void deepseek_topk_router(
    const float* __restrict__ logits,
    const float* __restrict__ bias,
    float* __restrict__ out,   // [T*8] indices (as float) then [T*8] weights
    int T) {
  const int t = blockIdx.x * 256 + threadIdx.x;
  if (t >= T) return;

  const float4* row4 = reinterpret_cast<const float4*>(logits + (size_t)t * N_EXPERTS);

  float lv[N_GROUP][8];
  float li[N_GROUP][8];

#pragma unroll
  for (int g = 0; g < N_GROUP; ++g) {
#pragma unroll
    for (int k = 0; k < 8; ++k) { lv[g][k] = -INFINITY; li[g][k] = 0.0f; }
    for (int q = 0; q < 8; ++q) {          // 32 experts per group, 4 per float4
      const float4 x = row4[g * 8 + q];
      const float xs[4] = {x.x, x.y, x.z, x.w};
#pragma unroll
      for (int e = 0; e < 4; ++e) {
        const int idx = g * EG + q * 4 + e;
        const float s = 1.0f / (1.0f + expf(-xs[e]));  // precise sigmoid (fp32)
        const float c = s + bias[idx];                 // corrected score
        insert8(lv[g], li[g], c, (float)idx);
      }
    }
  }

  // group scores = sum of top-2 corrected scores
  float gs[N_GROUP];
#pragma unroll
  for (int g = 0; g < N_GROUP; ++g) gs[g] = lv[g][0] + lv[g][1];

  // top-4 groups by rank (ties -> lower group index)
#pragma unroll
  for (int g = 0; g < N_GROUP; ++g) {
    int rank = 0;
#pragma unroll
    for (int h = 0; h < N_GROUP; ++h)
      rank += ((gs[h] > gs[g]) || (gs[h] == gs[g] && h < g)) ? 1 : 0;
    const bool sel = (rank < TOPK_GROUP);
    // mask: reference uses where(mask, c, 0.0)
#pragma unroll
    for (int k = 0; k < 8; ++k) lv[g][k] = sel ? lv[g][k] : 0.0f;
  }

  // merge tree: 8 sorted lists -> top-8
  float m0v[8], m0i[8], m1v[8], m1i[8], m2v[8], m2i[8], m3v[8], m3i[8];
  merge8(lv[0], li[0], lv[1], li[1], m0v, m0i);
  merge8(lv[2], li[2], lv[3], li[3], m1v, m1i);
  merge8(lv[4], li[4], lv[5], li[5], m2v, m2i);
  merge8(lv[6], li[6], lv[7], li[7], m3v, m3i);
  float n0v[8], n0i[8], n1v[8], n1i[8];
  merge8(m0v, m0i, m1v, m1i, n0v, n0i);
  merge8(m2v, m2i, m3v, m3i, n1v, n1i);
  float fv[8], fi[8];
  merge8(n0v, n0i, n1v, n1i, fv, fi);

  // weights: s = c - bias[idx]; normalize; * 2.5
  float sv[8];
  float sum = 0.0f;
#pragma unroll
  for (int k = 0; k < TOP_K; ++k) {
    const int id = (int)fi[k];
    sv[k] = fv[k] - bias[id];
    sum += sv[k];
  }
  const float denom = sum + 1e-20f;
  const float scale = 2.5f / denom;

  // output: indices (as float) at [0, T*8), weights at [T*8, 2*T*8)
  float4* oi = reinterpret_cast<float4*>(out) + (size_t)t * 2;
  oi[0] = make_float4(fi[0], fi[1], fi[2], fi[3]);
  oi[1] = make_float4(fi[4], fi[5], fi[6], fi[7]);
  float4* ow = reinterpret_cast<float4*>(out + (size_t)T * TOP_K) + (size_t)t * 2;
  ow[0] = make_float4(sv[0] * scale, sv[1] * scale, sv[2] * scale, sv[3] * scale);
  ow[1] = make_float4(sv[4] * scale, sv[5] * scale, sv[6] * scale, sv[7] * scale);
}

extern "C" void kernel_launch(void* const* d_in, const int* in_sizes, int n_in,
                              void* d_out, int out_size, void* d_ws, size_t ws_size,
                              hipStream_t stream) {
  const float* logits = (const float*)d_in[0];
  const float* bias   = (const float*)d_in[1];
  float* out = (float*)d_out;
  const int T = in_sizes[0] / N_EXPERTS;
  const int blocks = (T + 255) / 256;
  deepseek_topk_router<<<blocks, 256, 0, stream>>>(logits, bias, out, T);
}

// Round 5
// 217.761 us; speedup vs baseline: 1.1503x; 1.1503x over previous
//
#include <hip/hip_runtime.h>
#include <math.h>

// DeepseekV3 TopK router, MI355X — R5: 8 lanes per token, one 32-expert group
// per lane; per-lane sorted top-8 in registers; group selection and the
// 3-round merge tree exchange data through LDS (conflict-free [k][tid]
// layout) instead of shuffles. __launch_bounds__(256,2) as in the
// known-good R1 kernel. Requires T % 32 == 0 (T = 131072 here) so every
// block is full and barriers are uniform.

constexpr int N_EXPERTS   = 256;
constexpr int N_GROUP     = 8;
constexpr int EG          = 32;   // experts per group
constexpr int TOPK_GROUP  = 4;
constexpr int TOP_K       = 8;
constexpr int BLOCK       = 256;

// Insert (v,i) into a descending sorted-8 list. Strict '>' keeps
// lower-index-first on ties (stream indices are ascending).
__device__ __forceinline__ void insert8(float (&lv)[8], float (&li)[8], float v, float i) {
#pragma unroll
  for (int k = 0; k < 8; ++k) {
    const bool gt = v > lv[k];
    const float nv = gt ? lv[k] : v;
    const float ni = gt ? li[k] : i;
    lv[k] = gt ? v : lv[k];
    li[k] = gt ? i : li[k];
    v = nv; i = ni;
  }
}

// Total order: (value desc, index asc on ties).
__device__ __forceinline__ bool keyGE(float va, float ia, float vb, float ib) {
  return (va > vb) || (va == vb && ia < ib);
}

__device__ __forceinline__ void takeMax(float va, float ia, float vb, float ib,
                                        float& vo, float& io) {
  const bool a = keyGE(va, ia, vb, ib);
  vo = a ? va : vb;
  io = a ? ia : ib;
}

__device__ __forceinline__ void cswap(float& va, float& ia, float& vb, float& ib) {
  const bool a = keyGE(va, ia, vb, ib);
  const float v1 = a ? va : vb, i1 = a ? ia : ib;
  const float v2 = a ? vb : va, i2 = a ? ib : ia;
  va = v1; ia = i1; vb = v2; ib = i2;
}

// Top-8 of two descending sorted-8 lists -> descending sorted-8.
__device__ __forceinline__ void merge8(const float (&Av)[8], const float (&Ai)[8],
                                       const float (&Bv)[8], const float (&Bi)[8],
                                       float (&Rv)[8], float (&Ri)[8]) {
#pragma unroll
  for (int i = 0; i < 8; ++i) takeMax(Av[i], Ai[i], Bv[7 - i], Bi[7 - i], Rv[i], Ri[i]);
#pragma unroll
  for (int i = 0; i < 4; ++i) cswap(Rv[i], Ri[i], Rv[i + 4], Ri[i + 4]);
  cswap(Rv[0], Ri[0], Rv[2], Ri[2]);
  cswap(Rv[1], Ri[1], Rv[3], Ri[3]);
  cswap(Rv[4], Ri[4], Rv[6], Ri[6]);
  cswap(Rv[5], Ri[5], Rv[7], Ri[7]);
  cswap(Rv[0], Ri[0], Rv[1], Ri[1]);
  cswap(Rv[2], Ri[2], Rv[3], Ri[3]);
  cswap(Rv[4], Ri[4], Rv[5], Ri[5]);
  cswap(Rv[6], Ri[6], Rv[7], Ri[7]);
}

__global__ __launch_bounds__(256, 2) void deepseek_topk_router_lds(
    const float* __restrict__ logits,
    const float* __restrict__ bias,
    float* __restrict__ out,   // [T*8] indices (as float) then [T*8] weights
    int T) {
  __shared__ float gsbuf[BLOCK];        // 1 KB: group scores
  __shared__ float exv[8 * BLOCK];      // 8 KB: merge exchange, values
  __shared__ float exi[8 * BLOCK];      // 8 KB: merge exchange, indices

  const int tid = threadIdx.x;
  const int id  = blockIdx.x * BLOCK + tid;
  const int t   = id >> 3;              // token
  const int q   = id & 7;               // group handled by this lane

  const float4* row4 =
      reinterpret_cast<const float4*>(logits + (size_t)t * N_EXPERTS + q * EG);
  const float4* b4 = reinterpret_cast<const float4*>(bias + q * EG);

  // sorted top-8 of my group's 32 corrected scores (8 independent-iteration
  // loads, one serial 32-insert chain — hidden by high wave count)
  float lv[8], li[8];
#pragma unroll
  for (int k = 0; k < 8; ++k) { lv[k] = -INFINITY; li[k] = 0.0f; }

#pragma unroll
  for (int u = 0; u < 8; ++u) {
    const float4 x = row4[u];
    const float4 bb = b4[u];
    const float xs[4] = {x.x, x.y, x.z, x.w};
    const float bs[4] = {bb.x, bb.y, bb.z, bb.w};
#pragma unroll
    for (int e = 0; e < 4; ++e) {
      const int idx = q * EG + u * 4 + e;
      const float s = 1.0f / (1.0f + expf(-xs[e]));  // precise fp32 sigmoid
      const float c = s + bs[e];                     // corrected score
      insert8(lv, li, c, (float)idx);
    }
  }

  // group score = sum of top-2; exchange via LDS (stride-1 write, broadcast read)
  const float gs = lv[0] + lv[1];
  gsbuf[tid] = gs;
  __syncthreads();
  const int cbase = tid & ~7;           // my 8-lane cluster's base thread
  int rank = 0;
#pragma unroll
  for (int h = 0; h < N_GROUP; ++h) {
    const float other = gsbuf[cbase + h];
    rank += ((other > gs) || (other == gs && h < q)) ? 1 : 0;
  }
  const bool sel = (rank < TOPK_GROUP);
#pragma unroll
  for (int k = 0; k < 8; ++k) lv[k] = sel ? lv[k] : 0.0f;  // where(mask, c, 0)

  // merge tree across the 8-lane cluster via LDS: partner distances 1, 2, 4.
  // Layout ex[k*BLOCK + tid]: bank = tid%32 -> 2 lanes/bank (free).
  float pv[8], pi[8], rv[8], ri[8];
#pragma unroll
  for (int d = 1; d <= 4; d <<= 1) {
    __syncthreads();                    // protect previous round's reads
#pragma unroll
    for (int k = 0; k < 8; ++k) {
      exv[k * BLOCK + tid] = lv[k];
      exi[k * BLOCK + tid] = li[k];
    }
    __syncthreads();
    const int p = tid ^ d;              // partner (same cluster, d < 8)
#pragma unroll
    for (int k = 0; k < 8; ++k) {
      pv[k] = exv[k * BLOCK + p];
      pi[k] = exi[k * BLOCK + p];
    }
    merge8(lv, li, pv, pi, rv, ri);
#pragma unroll
    for (int k = 0; k < 8; ++k) { lv[k] = rv[k]; li[k] = ri[k]; }
  }
  // lv/li now hold the final top-8 (identical in all 8 lanes of the cluster)

  // weights: s = c - bias[idx]; normalize; * 2.5  (bias is L1-hot, 1 KB)
  float sv[8];
  float sum = 0.0f;
#pragma unroll
  for (int k = 0; k < TOP_K; ++k) {
    const int idf = (int)li[k];
    sv[k] = lv[k] - bias[idf];
    sum += sv[k];
  }
  const float scale = 2.5f / (sum + 1e-20f);

  // output: indices (as float) at [0, T*8), weights at [T*8, 2*T*8)
  // lanes 0..3 of each 8-lane cluster each write one float4
  if (q < 4) {
    float4 vout;
    if (q == 0)      vout = make_float4(li[0], li[1], li[2], li[3]);
    else if (q == 1) vout = make_float4(li[4], li[5], li[6], li[7]);
    else if (q == 2) vout = make_float4(sv[0] * scale, sv[1] * scale,
                                        sv[2] * scale, sv[3] * scale);
    else             vout = make_float4(sv[4] * scale, sv[5] * scale,
                                        sv[6] * scale, sv[7] * scale);
    const size_t half = (q < 2) ? 0 : (size_t)T * TOP_K;
    const int    sub  = q & 1;
    float4* dst = reinterpret_cast<float4*>(out + half) + (size_t)t * 2 + sub;
    *dst = vout;
  }
}

extern "C" void kernel_launch(void* const* d_in, const int* in_sizes, int n_in,
                              void* d_out, int out_size, void* d_ws, size_t ws_size,
                              hipStream_t stream) {
  const float* logits = (const float*)d_in[0];
  const float* bias   = (const float*)d_in[1];
  float* out = (float*)d_out;
  const int T = in_sizes[0] / N_EXPERTS;           // 131072 (multiple of 32)
  const long threads = (long)T * N_GROUP;          // 8 lanes per token
  const int blocks = (int)((threads + BLOCK - 1) / BLOCK);
  deepseek_topk_router_lds<<<blocks, BLOCK, 0, stream>>>(logits, bias, out, T);
}